// Round 13
// baseline (59.951 us; speedup 1.0000x reference)
//
#include <hip/hip_runtime.h>
#include <stdint.h>

#define NB   8
#define NN   2048
#define FIN  128
#define FOUT 64
#define LCAP 192

__device__ __forceinline__ uint32_t rotl32(uint32_t x, uint32_t r) {
  return (x << r) | (x >> (32u - r));
}

// JAX threefry2x32 with key = (0, 42)
__device__ __forceinline__ void threefry_0_42(uint32_t x0, uint32_t x1,
                                              uint32_t& o0, uint32_t& o1) {
  const uint32_t k0 = 0u, k1 = 42u;
  const uint32_t k2 = 0x1BD11BDAu ^ k0 ^ k1;
  x0 += k0; x1 += k1;
#define TFR(r) { x0 += x1; x1 = rotl32(x1, r); x1 ^= x0; }
  TFR(13u) TFR(15u) TFR(26u) TFR(6u)   x0 += k1; x1 += k2 + 1u;
  TFR(17u) TFR(29u) TFR(16u) TFR(24u)  x0 += k2; x1 += k0 + 2u;
  TFR(13u) TFR(15u) TFR(26u) TFR(6u)   x0 += k0; x1 += k1 + 3u;
  TFR(17u) TFR(29u) TFR(16u) TFR(24u)  x0 += k1; x1 += k2 + 4u;
  TFR(13u) TFR(15u) TFR(26u) TFR(6u)   x0 += k2; x1 += k0 + 5u;
#undef TFR
  o0 = x0; o1 = x1;
}

// Partitionable threefry: bits = o0^o1 of threefry(key, 0, v); keep iff bit31==0.
__device__ __forceinline__ bool keep_bit(uint32_t v) {
  uint32_t o0, o1;
  threefry_0_42(0u, v, o0, o1);
  return !((o0 ^ o1) >> 31);
}

// async 16B-per-lane global -> LDS copy (no VGPR payload).
// LDS dest is wave-uniform base; HW adds lane*16. Global src is per-lane.
__device__ __forceinline__ void async_copy16(const void* g, void* l) {
  __builtin_amdgcn_global_load_lds(
      (const __attribute__((address_space(1))) void*)g,
      (__attribute__((address_space(3))) void*)l, 16, 0, 0);
}

// Kernel A: Wh = h @ W, Wh1 = Wh@a[:64], Wh2 = Wh@a[64:]
// 4 rows/wave, scalar accumulators (proven ~5 us).
__global__ __launch_bounds__(256) void wh_kernel(
    const float* __restrict__ h, const float* __restrict__ W,
    const float* __restrict__ a, float* __restrict__ Wh,
    float* __restrict__ Wh1, float* __restrict__ Wh2) {
  __shared__ __align__(16) float wLds[FIN * FOUT];   // 32 KB
  __shared__ __align__(16) float hLds[16][FIN];      // 8 KB
  const int t = threadIdx.x;
  const int wv = t >> 6, lane = t & 63;
  const int rbase = blockIdx.x * 16;
  {
    const float4* W4 = reinterpret_cast<const float4*>(W);
    float4* wL4 = reinterpret_cast<float4*>(wLds);
    for (int idx = t; idx < FIN * FOUT / 4; idx += 256) wL4[idx] = W4[idx];
    const float4* h4 = reinterpret_cast<const float4*>(h + (size_t)rbase * FIN);
    float4* hL4 = reinterpret_cast<float4*>(&hLds[0][0]);
    for (int idx = t; idx < 16 * FIN / 4; idx += 256) hL4[idx] = h4[idx];
  }
  __syncthreads();
  const int r0 = wv * 4;
  float acc0 = 0.f, acc1 = 0.f, acc2 = 0.f, acc3 = 0.f;
#pragma unroll 4
  for (int k = 0; k < FIN; ++k) {
    const float w = wLds[k * FOUT + lane];
    acc0 += hLds[r0 + 0][k] * w;
    acc1 += hLds[r0 + 1][k] * w;
    acc2 += hLds[r0 + 2][k] * w;
    acc3 += hLds[r0 + 3][k] * w;
  }
  const float a1 = a[lane], a2 = a[FOUT + lane];
  float accs[4] = {acc0, acc1, acc2, acc3};
#pragma unroll
  for (int r = 0; r < 4; ++r) {
    const int row = rbase + r0 + r;
    Wh[(size_t)row * FOUT + lane] = accs[r];
    float x1 = accs[r] * a1, x2 = accs[r] * a2;
#pragma unroll
    for (int off = 32; off >= 1; off >>= 1) {
      x1 += __shfl_xor(x1, off);
      x2 += __shfl_xor(x2, off);
    }
    if (lane == 0) { Wh1[row] = x1; Wh2[row] = x2; }
  }
}

// Kernel B v9: ONE WAVE = ONE ROW, zero barriers, zero cross-wave coupling.
// adj row staged via global_load_lds DMA (no VGPR payload -> all 8 chunk
// copies in flight; fixes r7/r10's compiler-serialized loads). Wh2 row in
// 8 float4 regs issued under the same stall window.
// Max-free softmax: p~ = double with value 2^(q), q = LR(wh1+w)*log2e - 512,
// built by adding round(q) into the double exponent field (range-safe).
// One 6-hop 64-bit shfl reduce -> S. Survivor test in log domain
// (q > log2(1e-10*S)); pass-2 recompute with chunk skip; keep_bit fused;
// (j, coef) pushed to per-wave LDS list; serial-free PV gather.
__global__ __launch_bounds__(256) void attn_kernel(
    const int* __restrict__ adj, const float* __restrict__ Wh,
    const float* __restrict__ Wh1, const float* __restrict__ Wh2,
    float* __restrict__ out) {
  __shared__ __align__(16) int adjL[4][NN];   // 32 KB (8 KB per wave)
  __shared__ int   jlist[4][LCAP];            // 3 KB
  __shared__ float clist[4][LCAP];            // 3 KB
  __shared__ int   cntL[4];

  const int t = threadIdx.x;
  const int wv = t >> 6, lane = t & 63;
  const int r = blockIdx.x * 4 + wv;          // row = b*NN + i, 0..16383
  const int b = r >> 11;

  const int*   arow = adj + (size_t)r * NN;
  const float* wrow = Wh2 + (size_t)b * NN;

  // 1) issue async adj DMA (8 x 1KB) + Wh2 reg loads under the same window
#pragma unroll
  for (int c = 0; c < 8; ++c)
    async_copy16(arow + c * 256 + lane * 4, &adjL[wv][c * 256]);
  float4 w4[8];
#pragma unroll
  for (int c = 0; c < 8; ++c)
    w4[c] = *reinterpret_cast<const float4*>(wrow + c * 256 + lane * 4);
  const float wh1 = Wh1[r];
  if (lane == 0) cntL[wv] = 0;

  asm volatile("s_waitcnt vmcnt(0)" ::: "memory");

  // 2) pass 1: double-exp sum, no max needed
  double S = 0.0;
  float cmax[8];
#pragma unroll
  for (int c = 0; c < 8; ++c) {
    const int4 av = *reinterpret_cast<const int4*>(&adjL[wv][c * 256 + lane * 4]);
    const int aa[4] = {av.x, av.y, av.z, av.w};
    const float wf[4] = {w4[c].x, w4[c].y, w4[c].z, w4[c].w};
    float cm = -1.0e30f;
#pragma unroll
    for (int e = 0; e < 4; ++e) {
      const float ww = __int_as_float(__float_as_int(wf[e]) & (-aa[e]));
      const float x = wh1 + ww;
      const float lr = fmaxf(x, 0.2f * x);               // leaky-relu
      const float q = fmaf(lr, 1.44269504f, -512.0f);    // log2 domain, offset
      const float nf = rintf(q);
      const float m = __builtin_amdgcn_exp2f(q - nf);    // in [0.707, 1.414]
      double d = (double)m;
      d = __longlong_as_double(__double_as_longlong(d) +
                               ((long long)(int)nf << 52));
      S += d;
      cm = fmaxf(cm, q);
    }
    cmax[c] = cm;
  }
#pragma unroll
  for (int off = 1; off < 64; off <<= 1) S += __shfl_xor(S, off);

  // log-domain survivor threshold: q > log2(1e-10 * S)
  const unsigned long long sb = (unsigned long long)__double_as_longlong(S);
  const int E = (int)((sb >> 52) & 0x7ffull) - 1023;
  const double mant = __longlong_as_double(
      (long long)((sb & 0xFFFFFFFFFFFFFull) | 0x3FF0000000000000ull));
  const float qthr = (float)E + __log2f((float)mant) - 33.219281f;
  const double invS2 = 2.0 / S;   // dropout 1/(1-p)=2 folded in

  // 3) pass 2: recompute q, survivors only; fused keep_bit; push (j, coef)
  const uint32_t vbase = (uint32_t)r << 11;
#pragma unroll
  for (int c = 0; c < 8; ++c) {
    if (!__any(cmax[c] > qthr)) continue;     // wave-uniform chunk skip
    const int4 av = *reinterpret_cast<const int4*>(&adjL[wv][c * 256 + lane * 4]);
    const int aa[4] = {av.x, av.y, av.z, av.w};
    const float wf[4] = {w4[c].x, w4[c].y, w4[c].z, w4[c].w};
#pragma unroll
    for (int e = 0; e < 4; ++e) {
      const float ww = __int_as_float(__float_as_int(wf[e]) & (-aa[e]));
      const float x = wh1 + ww;
      const float lr = fmaxf(x, 0.2f * x);
      const float q = fmaf(lr, 1.44269504f, -512.0f);
      if (q > qthr) {                         // rare (few lanes)
        const int j = c * 256 + lane * 4 + e;
        if (keep_bit(vbase | (uint32_t)j)) {
          const float nf = rintf(q);
          const float m = __builtin_amdgcn_exp2f(q - nf);
          double d = (double)m;
          d = __longlong_as_double(__double_as_longlong(d) +
                                   ((long long)(int)nf << 52));
          const float coef = (float)(d * invS2);
          const int idx = atomicAdd(&cntL[wv], 1);
          if (idx < LCAP) { jlist[wv][idx] = j; clist[wv][idx] = coef; }
        }
      }
    }
  }

  // 4) PV gather over the per-wave survivor list (no barrier: same wave)
  float acc = 0.f;
  const int cnt = min(cntL[wv], LCAP);
  for (int idx = 0; idx < cnt; ++idx) {
    const int j = jlist[wv][idx];             // broadcast LDS reads
    const float cc = clist[wv][idx];
    acc += cc * Wh[((size_t)(b * NN + j)) * FOUT + lane];
  }
  out[(size_t)r * FOUT + lane] = acc;
}

extern "C" void kernel_launch(void* const* d_in, const int* in_sizes, int n_in,
                              void* d_out, int out_size, void* d_ws, size_t ws_size,
                              hipStream_t stream) {
  const float* h   = (const float*)d_in[0];
  const int*   adj = (const int*)d_in[1];
  const float* W   = (const float*)d_in[2];
  const float* a   = (const float*)d_in[3];
  float* out = (float*)d_out;
  float* ws  = (float*)d_ws;

  float* Wh  = ws;                                 // 16384*64 floats
  float* Wh1 = ws + (size_t)NB * NN * FOUT;        // 16384
  float* Wh2 = Wh1 + NB * NN;                      // 16384

  wh_kernel<<<dim3((NB * NN) / 16), dim3(256), 0, stream>>>(h, W, a, Wh, Wh1, Wh2);
  attn_kernel<<<dim3((NB * NN) / 4), dim3(256), 0, stream>>>(adj, Wh, Wh1, Wh2, out);
}